// Round 8
// baseline (406.087 us; speedup 1.0000x reference)
//
#include <hip/hip_runtime.h>
#include <hip/hip_bf16.h>
#include <hip/hip_cooperative_groups.h>
#include <stdint.h>

namespace cg = cooperative_groups;

#define NB   8
#define NN   2048
#define NE   16384
#define OBS  128
#define HID  256
#define OUTF 1024
#define BCAP 64     // per-node bucket capacity (mean deg 8, sigma 2.8)
#define NBLK 512
#define NTHR 256
#define NTH  (NBLK * NTHR)   // 131072 threads
#define NWAVE (NBLK * 4)     // 2048 waves

using bfrag = __attribute__((ext_vector_type(8))) short;
using ffrag = __attribute__((ext_vector_type(4))) float;

__device__ __forceinline__ short f2bf(float f) {
    __hip_bfloat16 h = __float2bfloat16(f);
    return __builtin_bit_cast(short, h);
}
__device__ __forceinline__ unsigned packbf(float a, float b) {
    return ((unsigned)(unsigned short)f2bf(b) << 16) | (unsigned)(unsigned short)f2bf(a);
}
__device__ __forceinline__ void gload_lds16(const void* g, void* l) {
    __builtin_amdgcn_global_load_lds(
        (const __attribute__((address_space(1))) unsigned int*)g,
        (__attribute__((address_space(3))) unsigned int*)l, 16, 0, 0);
}

// ================= cooperative mega-kernel (32KB LDS, 2+ blocks/CU) =================
__global__ __launch_bounds__(256, 2) void k_mega(
    const float* __restrict__ nodes, const int* __restrict__ edges,
    const float* __restrict__ W0, const float* __restrict__ b0,
    const float* __restrict__ W1, const float* __restrict__ b1,
    float* __restrict__ out,
    int* __restrict__ cnt, int* __restrict__ bucket,
    short* __restrict__ W0t, short* __restrict__ W1t,
    short* __restrict__ z0, short* __restrict__ x1, short* __restrict__ z1) {
    __shared__ short smem[16384];  // 32 KB
    const int tid = threadIdx.x, bid = blockIdx.x;
    const int gid = bid * NTHR + tid;
    const int lane = tid & 63, wid = tid >> 6;
    const int lrow = lane & 15, lk = (lane >> 4) * 8;
    cg::grid_group grid = cg::this_grid();

    // ---- P1: weight transposes (f32->bf16) + zero cnt ----
    for (int idx = gid; idx < HID * OUTF; idx += NTH) {  // 2 iters
        int n = idx / HID, k = idx - n * HID;
        W1t[idx] = f2bf(W1[k * OUTF + n]);
    }
    if (gid < OBS * HID) {
        int n = gid / OBS, k = gid - n * OBS;
        W0t[gid] = f2bf(W0[k * HID + n]);
    }
    if (gid < NB * NN) cnt[gid] = 0;
    grid.sync();

    // ---- P2: bucket scatter (1 edge/thread) ----
    {
        int b = gid >> 14, e = gid & (NE - 1);
        int src = edges[(size_t)b * 2 * NE + e];
        int dst = edges[(size_t)b * 2 * NE + NE + e];
        int pos = atomicAdd(&cnt[b * NN + dst], 1);
        if (pos < BCAP) bucket[((size_t)b * NN + dst) * BCAP + pos] = src;
    }
    grid.sync();

    // ---- P3: z0 = S.nodes (f32 -> bf16, F=128), wave per node, 8 rounds ----
    for (int w = bid * 4 + wid; w < NB * NN; w += NWAVE) {
        const int b = w >> 11, i = w & (NN - 1);
        const int* cb = cnt + b * NN;
        const int deg = cb[i];
        const float di = rsqrtf((float)(deg + 1));
        int s_t = 0;
        float dv_t = 0.f;
        if (lane < deg) {
            s_t = bucket[((size_t)b * NN + i) * BCAP + lane];
            dv_t = rsqrtf((float)(cb[s_t] + 1));
        }
        const float* xb = nodes + (size_t)b * NN * OBS;
        float2 v = *(const float2*)&xb[(size_t)i * OBS + lane * 2];
        float ax = di * di * v.x, ay = di * di * v.y;
        for (int e = 0; e < deg; ++e) {
            int s = __shfl(s_t, e);
            float wg = di * __shfl(dv_t, e);
            float2 u = *(const float2*)&xb[(size_t)s * OBS + lane * 2];
            ax = fmaf(wg, u.x, ax);
            ay = fmaf(wg, u.y, ay);
        }
        ((unsigned*)z0)[(((size_t)b * NN + i) * OBS + lane * 2) >> 1] = packbf(ax, ay);
    }
    grid.sync();

    // ---- P4: x1 = relu(z0 @ W0t^T + b0); 128x64 tiles, 512 tiles, 1/block ----
    {
        const int rtile = bid >> 2, ctile = bid & 3;
        const short* gA = z0 + (size_t)rtile * 128 * OBS;
        const short* gB = W0t + (size_t)ctile * 64 * OBS;
        short* As = smem;          // 16KB
        short* Bs = smem + 8192;   // 8KB
        ffrag acc[2][4] = {};
#pragma unroll
        for (int kt = 0; kt < 2; ++kt) {
#pragma unroll
            for (int c = 0; c < 4; ++c) {
                int off = c * 4096 + tid * 16;
                int row = off >> 7, kb = (off & 127) >> 1;
                gload_lds16(gA + (size_t)row * OBS + kt * 64 + kb, (char*)As + off);
            }
#pragma unroll
            for (int c = 0; c < 2; ++c) {
                int off = c * 4096 + tid * 16;
                int row = off >> 7, kb = (off & 127) >> 1;
                gload_lds16(gB + (size_t)row * OBS + kt * 64 + kb, (char*)Bs + off);
            }
            __syncthreads();
#pragma unroll
            for (int kk = 0; kk < 2; ++kk) {
                bfrag a[2], bf[4];
#pragma unroll
                for (int m = 0; m < 2; ++m)
                    a[m] = *(const bfrag*)&As[(wid * 32 + m * 16 + lrow) * 64 + kk * 32 + lk];
#pragma unroll
                for (int n = 0; n < 4; ++n)
                    bf[n] = *(const bfrag*)&Bs[(n * 16 + lrow) * 64 + kk * 32 + lk];
#pragma unroll
                for (int m = 0; m < 2; ++m)
#pragma unroll
                    for (int n = 0; n < 4; ++n)
                        acc[m][n] = __builtin_amdgcn_mfma_f32_16x16x32_bf16(a[m], bf[n], acc[m][n], 0, 0, 0);
            }
            __syncthreads();
        }
        const int orow = rtile * 128 + wid * 32 + (lane >> 4) * 4;
        const int ocol = ctile * 64 + lrow;
#pragma unroll
        for (int n = 0; n < 4; ++n) {
            float bv = b0[ocol + n * 16];
#pragma unroll
            for (int m = 0; m < 2; ++m)
#pragma unroll
                for (int r = 0; r < 4; ++r) {
                    float v = fmaxf(acc[m][n][r] + bv, 0.f);
                    x1[(size_t)(orow + m * 16 + r) * HID + ocol + n * 16] = f2bf(v);
                }
        }
    }
    grid.sync();

    // ---- P5: z1 = S.x1 (bf16, F=256), wave per node, 8 rounds ----
    for (int w = bid * 4 + wid; w < NB * NN; w += NWAVE) {
        const int b = w >> 11, i = w & (NN - 1);
        const int* cb = cnt + b * NN;
        const int deg = cb[i];
        const float di = rsqrtf((float)(deg + 1));
        int s_t = 0;
        float dv_t = 0.f;
        if (lane < deg) {
            s_t = bucket[((size_t)b * NN + i) * BCAP + lane];
            dv_t = rsqrtf((float)(cb[s_t] + 1));
        }
        const short* xb = x1 + (size_t)b * NN * HID;
        uint2 raw = *(const uint2*)&xb[(size_t)i * HID + lane * 4];
        const float di2 = di * di;
        float a0 = di2 * __uint_as_float(raw.x << 16);
        float a1 = di2 * __uint_as_float(raw.x & 0xffff0000u);
        float a2 = di2 * __uint_as_float(raw.y << 16);
        float a3 = di2 * __uint_as_float(raw.y & 0xffff0000u);
        for (int e = 0; e < deg; ++e) {
            int s = __shfl(s_t, e);
            float wg = di * __shfl(dv_t, e);
            uint2 u = *(const uint2*)&xb[(size_t)s * HID + lane * 4];
            a0 = fmaf(wg, __uint_as_float(u.x << 16), a0);
            a1 = fmaf(wg, __uint_as_float(u.x & 0xffff0000u), a1);
            a2 = fmaf(wg, __uint_as_float(u.y << 16), a2);
            a3 = fmaf(wg, __uint_as_float(u.y & 0xffff0000u), a3);
        }
        uint2 o;
        o.x = packbf(a0, a1);
        o.y = packbf(a2, a3);
        *(uint2*)&((unsigned*)z1)[(((size_t)b * NN + i) * HID + lane * 4) >> 1] = o;
    }
    grid.sync();

    // ---- P6: out = relu(z1 @ W1t^T + b1); 128x64 tiles, 2048 tiles, 4/block ----
    for (int t = bid; t < 2048; t += NBLK) {
        const int rtile = t >> 4, ctile = t & 15;
        const short* gA = z1 + (size_t)rtile * 128 * HID;
        const short* gB = W1t + (size_t)ctile * 64 * HID;
        short* As = smem;
        short* Bs = smem + 8192;
        ffrag acc[2][4] = {};
        for (int kt = 0; kt < 4; ++kt) {
#pragma unroll
            for (int c = 0; c < 4; ++c) {
                int off = c * 4096 + tid * 16;
                int row = off >> 7, kb = (off & 127) >> 1;
                gload_lds16(gA + (size_t)row * HID + kt * 64 + kb, (char*)As + off);
            }
#pragma unroll
            for (int c = 0; c < 2; ++c) {
                int off = c * 4096 + tid * 16;
                int row = off >> 7, kb = (off & 127) >> 1;
                gload_lds16(gB + (size_t)row * HID + kt * 64 + kb, (char*)Bs + off);
            }
            __syncthreads();
#pragma unroll
            for (int kk = 0; kk < 2; ++kk) {
                bfrag a[2], bf[4];
#pragma unroll
                for (int m = 0; m < 2; ++m)
                    a[m] = *(const bfrag*)&As[(wid * 32 + m * 16 + lrow) * 64 + kk * 32 + lk];
#pragma unroll
                for (int n = 0; n < 4; ++n)
                    bf[n] = *(const bfrag*)&Bs[(n * 16 + lrow) * 64 + kk * 32 + lk];
#pragma unroll
                for (int m = 0; m < 2; ++m)
#pragma unroll
                    for (int n = 0; n < 4; ++n)
                        acc[m][n] = __builtin_amdgcn_mfma_f32_16x16x32_bf16(a[m], bf[n], acc[m][n], 0, 0, 0);
            }
            __syncthreads();
        }
        const int orow = rtile * 128 + wid * 32 + (lane >> 4) * 4;
        const int ocol = ctile * 64 + lrow;
#pragma unroll
        for (int n = 0; n < 4; ++n) {
            float bv = b1[ocol + n * 16];
#pragma unroll
            for (int m = 0; m < 2; ++m)
#pragma unroll
                for (int r = 0; r < 4; ++r) {
                    float v = fmaxf(acc[m][n][r] + bv, 0.f);
                    out[(size_t)(orow + m * 16 + r) * OUTF + ocol + n * 16] = v;
                }
        }
    }
}

// ================= fallback chain (R6, proven 73us) =================
__global__ __launch_bounds__(256) void k_prep(const float* __restrict__ W0,
                                              const float* __restrict__ W1,
                                              short* __restrict__ W0t,
                                              short* __restrict__ W1t,
                                              int* __restrict__ cnt) {
    int idx = blockIdx.x * 256 + threadIdx.x;
    if (idx < HID * OUTF) {
        int n = idx / HID, k = idx - n * HID;
        W1t[idx] = f2bf(W1[k * OUTF + n]);
    }
    if (idx < OBS * HID) {
        int n = idx / OBS, k = idx - n * OBS;
        W0t[idx] = f2bf(W0[k * HID + n]);
    }
    if (idx < NB * NN) cnt[idx] = 0;
}

__global__ __launch_bounds__(256) void k_bucket(const int* __restrict__ edges,
                                                int* __restrict__ cnt,
                                                int* __restrict__ bucket) {
    int idx = blockIdx.x * 256 + threadIdx.x;
    if (idx >= NB * NE) return;
    int b = idx / NE, e = idx - b * NE;
    int src = edges[(size_t)b * 2 * NE + e];
    int dst = edges[(size_t)b * 2 * NE + NE + e];
    int pos = atomicAdd(&cnt[b * NN + dst], 1);
    if (pos < BCAP) bucket[((size_t)b * NN + dst) * BCAP + pos] = src;
}

__global__ __launch_bounds__(256) void k_agg0(const float* __restrict__ nodes,
                                              const int* __restrict__ cnt,
                                              const int* __restrict__ bucket,
                                              unsigned* __restrict__ z0) {
    const int b = blockIdx.y, t = threadIdx.x;
    const int i = blockIdx.x * 4 + (t >> 6);
    const int l = t & 63;
    const int* cb = cnt + b * NN;
    const int deg = cb[i];
    const float di = rsqrtf((float)(deg + 1));
    int s_t = 0;
    float dv_t = 0.f;
    if (l < deg) {
        s_t = bucket[((size_t)b * NN + i) * BCAP + l];
        dv_t = rsqrtf((float)(cb[s_t] + 1));
    }
    const float* xb = nodes + (size_t)b * NN * OBS;
    float2 v = *(const float2*)&xb[(size_t)i * OBS + l * 2];
    float ax = di * di * v.x, ay = di * di * v.y;
    for (int e = 0; e < deg; ++e) {
        int s = __shfl(s_t, e);
        float w = di * __shfl(dv_t, e);
        float2 u = *(const float2*)&xb[(size_t)s * OBS + l * 2];
        ax = fmaf(w, u.x, ax);
        ay = fmaf(w, u.y, ay);
    }
    z0[(((size_t)b * NN + i) * OBS + l * 2) >> 1] = packbf(ax, ay);
}

__global__ __launch_bounds__(256) void k_agg1(const short* __restrict__ x1,
                                              const int* __restrict__ cnt,
                                              const int* __restrict__ bucket,
                                              unsigned* __restrict__ z1) {
    const int b = blockIdx.y, t = threadIdx.x;
    const int i = blockIdx.x * 4 + (t >> 6);
    const int l = t & 63;
    const int* cb = cnt + b * NN;
    const int deg = cb[i];
    const float di = rsqrtf((float)(deg + 1));
    int s_t = 0;
    float dv_t = 0.f;
    if (l < deg) {
        s_t = bucket[((size_t)b * NN + i) * BCAP + l];
        dv_t = rsqrtf((float)(cb[s_t] + 1));
    }
    const short* xb = x1 + (size_t)b * NN * HID;
    uint2 raw = *(const uint2*)&xb[(size_t)i * HID + l * 4];
    const float di2 = di * di;
    float a0 = di2 * __uint_as_float(raw.x << 16);
    float a1 = di2 * __uint_as_float(raw.x & 0xffff0000u);
    float a2 = di2 * __uint_as_float(raw.y << 16);
    float a3 = di2 * __uint_as_float(raw.y & 0xffff0000u);
    for (int e = 0; e < deg; ++e) {
        int s = __shfl(s_t, e);
        float w = di * __shfl(dv_t, e);
        uint2 u = *(const uint2*)&xb[(size_t)s * HID + l * 4];
        a0 = fmaf(w, __uint_as_float(u.x << 16), a0);
        a1 = fmaf(w, __uint_as_float(u.x & 0xffff0000u), a1);
        a2 = fmaf(w, __uint_as_float(u.y << 16), a2);
        a3 = fmaf(w, __uint_as_float(u.y & 0xffff0000u), a3);
    }
    uint2 o;
    o.x = packbf(a0, a1);
    o.y = packbf(a2, a3);
    *(uint2*)&z1[(((size_t)b * NN + i) * HID + l * 4) >> 1] = o;
}

template <int K, int N, bool OUT_BF16>
__global__ __launch_bounds__(256, 2) void gemm_mfma(const short* __restrict__ A,
                                                    const short* __restrict__ Bt,
                                                    const float* __restrict__ bias,
                                                    void* __restrict__ Cv) {
    __shared__ short lds[2][2][128 * 64];
    constexpr int NC = N / 128;
    const int h = blockIdx.x;
    const int rtile = (h & 7) + 8 * (h / (8 * NC));
    const int ctile = (h >> 3) % NC;
    const int tid = threadIdx.x;
    const int lane = tid & 63;
    const int wid = tid >> 6;
    const int wr = wid >> 1, wc = wid & 1;
    const int lrow = lane & 15, lk = (lane >> 4) * 8;
    const int row0 = rtile * 128, col0 = ctile * 128;
    const short* gA = A + (size_t)row0 * K;
    const short* gB = Bt + (size_t)col0 * K;

    auto stage = [&](int buf, int kt) {
#pragma unroll
        for (int c = 0; c < 4; ++c) {
            int off = c * 4096 + tid * 16;
            int row = off >> 7, kb = off & 127;
            gload_lds16(gA + (size_t)row * K + kt + (kb >> 1), (char*)&lds[buf][0][0] + off);
            gload_lds16(gB + (size_t)row * K + kt + (kb >> 1), (char*)&lds[buf][1][0] + off);
        }
    };

    ffrag acc[4][4] = {};
    stage(0, 0);
    __syncthreads();
    const int NT = K / 64;
    int cur = 0;
    for (int kt = 0; kt < NT; ++kt) {
        if (kt + 1 < NT) stage(cur ^ 1, (kt + 1) * 64);
        const short* As = &lds[cur][0][0];
        const short* Bs = &lds[cur][1][0];
#pragma unroll
        for (int kk = 0; kk < 2; ++kk) {
            bfrag a[4], b[4];
#pragma unroll
            for (int m = 0; m < 4; ++m)
                a[m] = *(const bfrag*)&As[(wr * 64 + m * 16 + lrow) * 64 + kk * 32 + lk];
#pragma unroll
            for (int n = 0; n < 4; ++n)
                b[n] = *(const bfrag*)&Bs[(wc * 64 + n * 16 + lrow) * 64 + kk * 32 + lk];
#pragma unroll
            for (int m = 0; m < 4; ++m)
#pragma unroll
                for (int n = 0; n < 4; ++n)
                    acc[m][n] = __builtin_amdgcn_mfma_f32_16x16x32_bf16(a[m], b[n], acc[m][n], 0, 0, 0);
        }
        __syncthreads();
        cur ^= 1;
    }

    const int orow = row0 + wr * 64 + (lane >> 4) * 4;
    const int ocol = col0 + wc * 64 + lrow;
#pragma unroll
    for (int n = 0; n < 4; ++n) {
        float bv = bias[ocol + n * 16];
#pragma unroll
        for (int m = 0; m < 4; ++m) {
#pragma unroll
            for (int r = 0; r < 4; ++r) {
                float v = fmaxf(acc[m][n][r] + bv, 0.f);
                size_t idx = (size_t)(orow + m * 16 + r) * N + (ocol + n * 16);
                if constexpr (OUT_BF16)
                    ((short*)Cv)[idx] = f2bf(v);
                else
                    ((float*)Cv)[idx] = v;
            }
        }
    }
}

extern "C" void kernel_launch(void* const* d_in, const int* in_sizes, int n_in,
                              void* d_out, int out_size, void* d_ws, size_t ws_size,
                              hipStream_t stream) {
    const float* nodes = (const float*)d_in[0];
    const int*   edges = (const int*)d_in[1];
    const float* W0    = (const float*)d_in[2];
    const float* b0    = (const float*)d_in[3];
    const float* W1    = (const float*)d_in[4];
    const float* b1    = (const float*)d_in[5];
    float* out = (float*)d_out;

    char* ws = (char*)d_ws;
    size_t off = 0;
    auto alloc = [&](size_t bytes) -> char* {
        char* p = ws + off;
        off = (off + bytes + 255) & ~(size_t)255;
        return p;
    };
    int*   cnt    = (int*)alloc((size_t)NB * NN * 4);
    int*   bucket = (int*)alloc((size_t)NB * NN * BCAP * 4);   // 4 MB
    short* W0t    = (short*)alloc((size_t)HID * OBS * 2);
    short* W1t    = (short*)alloc((size_t)OUTF * HID * 2);
    short* z0     = (short*)alloc((size_t)NB * NN * OBS * 2);  // 4 MB
    short* x1     = (short*)alloc((size_t)NB * NN * HID * 2);  // 8 MB
    short* z1     = (short*)alloc((size_t)NB * NN * HID * 2);  // 8 MB

    // --- guarded cooperative path (host-side queries are capture-safe) ---
    int dev = 0;
    (void)hipGetDevice(&dev);
    int coopAttr = 0;
    (void)hipDeviceGetAttribute(&coopAttr, hipDeviceAttributeCooperativeLaunch, dev);
    int ncu = 0;
    (void)hipDeviceGetAttribute(&ncu, hipDeviceAttributeMultiprocessorCount, dev);
    int occ = 0;
    (void)hipOccupancyMaxActiveBlocksPerMultiprocessor(&occ, k_mega, NTHR, 0);

    if (coopAttr != 0 && (long)occ * ncu >= NBLK) {
        void* args[] = {
            (void*)&nodes, (void*)&edges, (void*)&W0, (void*)&b0, (void*)&W1, (void*)&b1,
            (void*)&out, (void*)&cnt, (void*)&bucket, (void*)&W0t, (void*)&W1t,
            (void*)&z0, (void*)&x1, (void*)&z1
        };
        hipError_t err = hipLaunchCooperativeKernel((void*)k_mega, dim3(NBLK), dim3(NTHR),
                                                    args, 0, stream);
        if (err == hipSuccess) return;
        (void)hipGetLastError();  // clear error state, fall through to chain
    }

    // --- fallback: proven R6 chain ---
    k_prep<<<(HID * OUTF + 255) / 256, 256, 0, stream>>>(W0, W1, W0t, W1t, cnt);
    k_bucket<<<(NB * NE + 255) / 256, 256, 0, stream>>>(edges, cnt, bucket);
    k_agg0<<<dim3(NN / 4, NB), 256, 0, stream>>>(nodes, cnt, bucket, (unsigned*)z0);
    gemm_mfma<OBS, HID, true><<<(NB * NN / 128) * (HID / 128), 256, 0, stream>>>(z0, W0t, b0, x1);
    k_agg1<<<dim3(NN / 4, NB), 256, 0, stream>>>(x1, cnt, bucket, (unsigned*)z1);
    gemm_mfma<HID, OUTF, false><<<(NB * NN / 128) * (OUTF / 128), 256, 0, stream>>>(z1, W1t, b1, out);
}

// Round 9
// 68.323 us; speedup vs baseline: 5.9437x; 5.9437x over previous
//
#include <hip/hip_runtime.h>
#include <hip/hip_bf16.h>
#include <stdint.h>

#define NB   8
#define NN   2048
#define NE   16384
#define OBS  128
#define HID  256
#define OUTF 1024
#define BCAP 64   // per-node bucket capacity (mean deg 8, sigma 2.8)

using bfrag = __attribute__((ext_vector_type(8))) short;
using ffrag = __attribute__((ext_vector_type(4))) float;

__device__ __forceinline__ short f2bf(float f) {
    __hip_bfloat16 h = __float2bfloat16(f);
    return __builtin_bit_cast(short, h);
}
__device__ __forceinline__ unsigned packbf(float a, float b) {
    return ((unsigned)(unsigned short)f2bf(b) << 16) | (unsigned)(unsigned short)f2bf(a);
}
__device__ __forceinline__ void gload_lds16(const void* g, void* l) {
    __builtin_amdgcn_global_load_lds(
        (const __attribute__((address_space(1))) unsigned int*)g,
        (__attribute__((address_space(3))) unsigned int*)l, 16, 0, 0);
}

// ---------------- prep: W0^T, W1^T (f32->bf16) + zero cnt ----------------
__global__ __launch_bounds__(256) void k_prep(const float* __restrict__ W0,
                                              const float* __restrict__ W1,
                                              short* __restrict__ W0t,
                                              short* __restrict__ W1t,
                                              int* __restrict__ cnt) {
    int idx = blockIdx.x * 256 + threadIdx.x;
    if (idx < HID * OUTF) {  // W1t [OUTF][HID]
        int n = idx / HID, k = idx - n * HID;
        W1t[idx] = f2bf(W1[k * OUTF + n]);
    }
    if (idx < OBS * HID) {   // W0t [HID][OBS]
        int n = idx / OBS, k = idx - n * OBS;
        W0t[idx] = f2bf(W0[k * HID + n]);
    }
    if (idx < NB * NN) cnt[idx] = 0;
}

// ---------------- bucket scatter: bucket[b][dst][cnt++] = src ----------------
__global__ __launch_bounds__(256) void k_bucket(const int* __restrict__ edges,
                                                int* __restrict__ cnt,
                                                int* __restrict__ bucket) {
    int idx = blockIdx.x * 256 + threadIdx.x;
    if (idx >= NB * NE) return;
    int b = idx / NE, e = idx - b * NE;
    int src = edges[(size_t)b * 2 * NE + e];
    int dst = edges[(size_t)b * 2 * NE + NE + e];
    int pos = atomicAdd(&cnt[b * NN + dst], 1);
    if (pos < BCAP) bucket[((size_t)b * NN + dst) * BCAP + pos] = src;
}

// ---------------- pre-GEMM aggregation z = S.x (wave per node) ----------------
// z0 = S . nodes  (f32 in -> bf16 out, F=128; 2 f32/lane)
__global__ __launch_bounds__(256) void k_agg0(const float* __restrict__ nodes,
                                              const int* __restrict__ cnt,
                                              const int* __restrict__ bucket,
                                              unsigned* __restrict__ z0) {
    const int b = blockIdx.y, t = threadIdx.x;
    const int i = blockIdx.x * 4 + (t >> 6);
    const int l = t & 63;
    const int* cb = cnt + b * NN;
    const int deg = cb[i];
    const int degc = deg < BCAP ? deg : BCAP;
    const float di = rsqrtf((float)(deg + 1));
    int s_t = 0;
    float dv_t = 0.f;
    if (l < degc) {
        s_t = bucket[((size_t)b * NN + i) * BCAP + l];
        dv_t = rsqrtf((float)(cb[s_t] + 1));
    }
    const float* xb = nodes + (size_t)b * NN * OBS;
    float2 v = *(const float2*)&xb[(size_t)i * OBS + l * 2];
    float ax = di * di * v.x, ay = di * di * v.y;
    float bx = 0.f, by = 0.f;
    int e = 0;
    for (; e + 2 <= degc; e += 2) {
        int sA = __shfl(s_t, e), sB = __shfl(s_t, e + 1);
        float wA = di * __shfl(dv_t, e), wB = di * __shfl(dv_t, e + 1);
        float2 uA = *(const float2*)&xb[(size_t)sA * OBS + l * 2];
        float2 uB = *(const float2*)&xb[(size_t)sB * OBS + l * 2];
        ax = fmaf(wA, uA.x, ax);
        ay = fmaf(wA, uA.y, ay);
        bx = fmaf(wB, uB.x, bx);
        by = fmaf(wB, uB.y, by);
    }
    if (e < degc) {
        int s = __shfl(s_t, e);
        float w = di * __shfl(dv_t, e);
        float2 u = *(const float2*)&xb[(size_t)s * OBS + l * 2];
        ax = fmaf(w, u.x, ax);
        ay = fmaf(w, u.y, ay);
    }
    ax += bx;
    ay += by;
    z0[(((size_t)b * NN + i) * OBS + l * 2) >> 1] = packbf(ax, ay);
}

// z1 = S . x1  (bf16 in -> bf16 out, F=256; 4 bf16/lane)
__global__ __launch_bounds__(256) void k_agg1(const short* __restrict__ x1,
                                              const int* __restrict__ cnt,
                                              const int* __restrict__ bucket,
                                              unsigned* __restrict__ z1) {
    const int b = blockIdx.y, t = threadIdx.x;
    const int i = blockIdx.x * 4 + (t >> 6);
    const int l = t & 63;
    const int* cb = cnt + b * NN;
    const int deg = cb[i];
    const int degc = deg < BCAP ? deg : BCAP;
    const float di = rsqrtf((float)(deg + 1));
    int s_t = 0;
    float dv_t = 0.f;
    if (l < degc) {
        s_t = bucket[((size_t)b * NN + i) * BCAP + l];
        dv_t = rsqrtf((float)(cb[s_t] + 1));
    }
    const short* xb = x1 + (size_t)b * NN * HID;
    uint2 raw = *(const uint2*)&xb[(size_t)i * HID + l * 4];
    const float di2 = di * di;
    float a0 = di2 * __uint_as_float(raw.x << 16);
    float a1 = di2 * __uint_as_float(raw.x & 0xffff0000u);
    float a2 = di2 * __uint_as_float(raw.y << 16);
    float a3 = di2 * __uint_as_float(raw.y & 0xffff0000u);
    float c0 = 0.f, c1 = 0.f, c2 = 0.f, c3 = 0.f;
    int e = 0;
    for (; e + 2 <= degc; e += 2) {
        int sA = __shfl(s_t, e), sB = __shfl(s_t, e + 1);
        float wA = di * __shfl(dv_t, e), wB = di * __shfl(dv_t, e + 1);
        uint2 uA = *(const uint2*)&xb[(size_t)sA * HID + l * 4];
        uint2 uB = *(const uint2*)&xb[(size_t)sB * HID + l * 4];
        a0 = fmaf(wA, __uint_as_float(uA.x << 16), a0);
        a1 = fmaf(wA, __uint_as_float(uA.x & 0xffff0000u), a1);
        a2 = fmaf(wA, __uint_as_float(uA.y << 16), a2);
        a3 = fmaf(wA, __uint_as_float(uA.y & 0xffff0000u), a3);
        c0 = fmaf(wB, __uint_as_float(uB.x << 16), c0);
        c1 = fmaf(wB, __uint_as_float(uB.x & 0xffff0000u), c1);
        c2 = fmaf(wB, __uint_as_float(uB.y << 16), c2);
        c3 = fmaf(wB, __uint_as_float(uB.y & 0xffff0000u), c3);
    }
    if (e < degc) {
        int s = __shfl(s_t, e);
        float w = di * __shfl(dv_t, e);
        uint2 u = *(const uint2*)&xb[(size_t)s * HID + l * 4];
        a0 = fmaf(w, __uint_as_float(u.x << 16), a0);
        a1 = fmaf(w, __uint_as_float(u.x & 0xffff0000u), a1);
        a2 = fmaf(w, __uint_as_float(u.y << 16), a2);
        a3 = fmaf(w, __uint_as_float(u.y & 0xffff0000u), a3);
    }
    a0 += c0; a1 += c1; a2 += c2; a3 += c3;
    uint2 o;
    o.x = packbf(a0, a1);
    o.y = packbf(a2, a3);
    *(uint2*)&z1[(((size_t)b * NN + i) * HID + l * 4) >> 1] = o;
}

// ---------------- bf16 MFMA GEMM: C = relu(A @ Bt^T + bias) ----------------
// A [M][K] bf16 row-major, Bt [N][K] bf16 (pre-transposed weights).
// 128x128 tile, templated BK (32 -> 32KB LDS, 3 blocks/CU), double-buffered,
// global_load_lds width-16 staging. XCD-grouped 1D grid remap.
template <int K, int N, bool OUT_BF16, int BK>
__global__ __launch_bounds__(256, 3) void gemm_mfma(const short* __restrict__ A,
                                                    const short* __restrict__ Bt,
                                                    const float* __restrict__ bias,
                                                    void* __restrict__ Cv) {
    __shared__ short lds[2][2][128 * BK];
    constexpr int NC = N / 128;
    constexpr int CH = (128 * BK * 2) / 4096;  // 4KB chunks per tile
    const int h = blockIdx.x;
    const int rtile = (h & 7) + 8 * (h / (8 * NC));
    const int ctile = (h >> 3) % NC;
    const int tid = threadIdx.x;
    const int lane = tid & 63;
    const int wid = tid >> 6;
    const int wr = wid >> 1, wc = wid & 1;
    const int lrow = lane & 15, lk = (lane >> 4) * 8;
    const int row0 = rtile * 128, col0 = ctile * 128;
    const short* gA = A + (size_t)row0 * K;
    const short* gB = Bt + (size_t)col0 * K;

    auto stage = [&](int buf, int kt) {
#pragma unroll
        for (int c = 0; c < CH; ++c) {
            int off = c * 4096 + tid * 16;
            int row = off / (2 * BK), kb = (off % (2 * BK)) >> 1;
            gload_lds16(gA + (size_t)row * K + kt + kb, (char*)&lds[buf][0][0] + off);
            gload_lds16(gB + (size_t)row * K + kt + kb, (char*)&lds[buf][1][0] + off);
        }
    };

    ffrag acc[4][4] = {};
    stage(0, 0);
    __syncthreads();
    const int NT = K / BK;
    int cur = 0;
    for (int kt = 0; kt < NT; ++kt) {
        if (kt + 1 < NT) stage(cur ^ 1, (kt + 1) * BK);
        const short* As = &lds[cur][0][0];
        const short* Bs = &lds[cur][1][0];
#pragma unroll
        for (int kk = 0; kk < BK / 32; ++kk) {
            bfrag a[4], b[4];
#pragma unroll
            for (int m = 0; m < 4; ++m)
                a[m] = *(const bfrag*)&As[(wr * 64 + m * 16 + lrow) * BK + kk * 32 + lk];
#pragma unroll
            for (int n = 0; n < 4; ++n)
                b[n] = *(const bfrag*)&Bs[(wc * 64 + n * 16 + lrow) * BK + kk * 32 + lk];
#pragma unroll
            for (int m = 0; m < 4; ++m)
#pragma unroll
                for (int n = 0; n < 4; ++n)
                    acc[m][n] = __builtin_amdgcn_mfma_f32_16x16x32_bf16(a[m], b[n], acc[m][n], 0, 0, 0);
        }
        __syncthreads();
        cur ^= 1;
    }

    const int orow = row0 + wr * 64 + (lane >> 4) * 4;
    const int ocol = col0 + wc * 64 + lrow;
#pragma unroll
    for (int n = 0; n < 4; ++n) {
        float bv = bias[ocol + n * 16];
#pragma unroll
        for (int m = 0; m < 4; ++m) {
#pragma unroll
            for (int r = 0; r < 4; ++r) {
                float v = fmaxf(acc[m][n][r] + bv, 0.f);
                size_t idx = (size_t)(orow + m * 16 + r) * N + (ocol + n * 16);
                if constexpr (OUT_BF16)
                    ((short*)Cv)[idx] = f2bf(v);
                else
                    ((float*)Cv)[idx] = v;
            }
        }
    }
}

extern "C" void kernel_launch(void* const* d_in, const int* in_sizes, int n_in,
                              void* d_out, int out_size, void* d_ws, size_t ws_size,
                              hipStream_t stream) {
    const float* nodes = (const float*)d_in[0];
    const int*   edges = (const int*)d_in[1];
    const float* W0    = (const float*)d_in[2];
    const float* b0    = (const float*)d_in[3];
    const float* W1    = (const float*)d_in[4];
    const float* b1    = (const float*)d_in[5];
    float* out = (float*)d_out;

    char* ws = (char*)d_ws;
    size_t off = 0;
    auto alloc = [&](size_t bytes) -> char* {
        char* p = ws + off;
        off = (off + bytes + 255) & ~(size_t)255;
        return p;
    };
    int*   cnt    = (int*)alloc((size_t)NB * NN * 4);
    int*   bucket = (int*)alloc((size_t)NB * NN * BCAP * 4);   // 4 MB
    short* W0t    = (short*)alloc((size_t)HID * OBS * 2);
    short* W1t    = (short*)alloc((size_t)OUTF * HID * 2);
    short* z0     = (short*)alloc((size_t)NB * NN * OBS * 2);  // 4 MB
    short* x1     = (short*)alloc((size_t)NB * NN * HID * 2);  // 8 MB
    short* z1     = (short*)alloc((size_t)NB * NN * HID * 2);  // 8 MB

    k_prep<<<(HID * OUTF + 255) / 256, 256, 0, stream>>>(W0, W1, W0t, W1t, cnt);
    k_bucket<<<(NB * NE + 255) / 256, 256, 0, stream>>>(edges, cnt, bucket);
    k_agg0<<<dim3(NN / 4, NB), 256, 0, stream>>>(nodes, cnt, bucket, (unsigned*)z0);
    gemm_mfma<OBS, HID, true, 32><<<(NB * NN / 128) * (HID / 128), 256, 0, stream>>>(z0, W0t, b0, x1);
    k_agg1<<<dim3(NN / 4, NB), 256, 0, stream>>>(x1, cnt, bucket, (unsigned*)z1);
    gemm_mfma<HID, OUTF, false, 32><<<(NB * NN / 128) * (OUTF / 128), 256, 0, stream>>>(z1, W1t, b1, out);
}

// Round 10
// 67.236 us; speedup vs baseline: 6.0397x; 1.0162x over previous
//
#include <hip/hip_runtime.h>
#include <hip/hip_bf16.h>
#include <stdint.h>

#define NB   8
#define NN   2048
#define NE   16384
#define OBS  128
#define HID  256
#define OUTF 1024
#define BCAP 64   // per-node bucket capacity (mean deg 8, sigma 2.8)

using bfrag = __attribute__((ext_vector_type(8))) short;
using ffrag = __attribute__((ext_vector_type(4))) float;

__device__ __forceinline__ short f2bf(float f) {
    __hip_bfloat16 h = __float2bfloat16(f);
    return __builtin_bit_cast(short, h);
}
__device__ __forceinline__ unsigned packbf(float a, float b) {
    return ((unsigned)(unsigned short)f2bf(b) << 16) | (unsigned)(unsigned short)f2bf(a);
}
__device__ __forceinline__ void gload_lds16(const void* g, void* l) {
    __builtin_amdgcn_global_load_lds(
        (const __attribute__((address_space(1))) unsigned int*)g,
        (__attribute__((address_space(3))) unsigned int*)l, 16, 0, 0);
}

// ---------------- prep: W0^T, W1^T (f32->bf16) + zero cnt ----------------
__global__ __launch_bounds__(256) void k_prep(const float* __restrict__ W0,
                                              const float* __restrict__ W1,
                                              short* __restrict__ W0t,
                                              short* __restrict__ W1t,
                                              int* __restrict__ cnt) {
    int idx = blockIdx.x * 256 + threadIdx.x;
    if (idx < HID * OUTF) {  // W1t [OUTF][HID]
        int n = idx / HID, k = idx - n * HID;
        W1t[idx] = f2bf(W1[k * OUTF + n]);
    }
    if (idx < OBS * HID) {   // W0t [HID][OBS]
        int n = idx / OBS, k = idx - n * OBS;
        W0t[idx] = f2bf(W0[k * HID + n]);
    }
    if (idx < NB * NN) cnt[idx] = 0;
}

// ---------------- bucket scatter: bucket[b][dst][cnt++] = src ----------------
__global__ __launch_bounds__(256) void k_bucket(const int* __restrict__ edges,
                                                int* __restrict__ cnt,
                                                int* __restrict__ bucket) {
    int idx = blockIdx.x * 256 + threadIdx.x;
    if (idx >= NB * NE) return;
    int b = idx / NE, e = idx - b * NE;
    int src = edges[(size_t)b * 2 * NE + e];
    int dst = edges[(size_t)b * 2 * NE + NE + e];
    int pos = atomicAdd(&cnt[b * NN + dst], 1);
    if (pos < BCAP) bucket[((size_t)b * NN + dst) * BCAP + pos] = src;
}

// ---------------- pre-GEMM aggregation z = S.x (wave per node, 4x MLP) ----------------
// z0 = S . nodes  (f32 in -> bf16 out, F=128; 2 f32/lane)
__global__ __launch_bounds__(256) void k_agg0(const float* __restrict__ nodes,
                                              const int* __restrict__ cnt,
                                              const int* __restrict__ bucket,
                                              unsigned* __restrict__ z0) {
    const int b = blockIdx.y, t = threadIdx.x;
    const int i = blockIdx.x * 4 + (t >> 6);
    const int l = t & 63;
    const int* cb = cnt + b * NN;
    const int deg = cb[i];
    const int degc = deg < BCAP ? deg : BCAP;
    const float di = rsqrtf((float)(deg + 1));
    int s_t = 0;
    float dv_t = 0.f;
    if (l < degc) {
        s_t = bucket[((size_t)b * NN + i) * BCAP + l];
        dv_t = rsqrtf((float)(cb[s_t] + 1));
    }
    const float* xb = nodes + (size_t)b * NN * OBS;
    float2 v = *(const float2*)&xb[(size_t)i * OBS + l * 2];
    float ax = di * di * v.x, ay = di * di * v.y;
    float bx = 0.f, by = 0.f;
    int e = 0;
    for (; e + 4 <= degc; e += 4) {
        int s0 = __shfl(s_t, e),     s1 = __shfl(s_t, e + 1);
        int s2 = __shfl(s_t, e + 2), s3 = __shfl(s_t, e + 3);
        float w0 = di * __shfl(dv_t, e),     w1 = di * __shfl(dv_t, e + 1);
        float w2 = di * __shfl(dv_t, e + 2), w3 = di * __shfl(dv_t, e + 3);
        float2 u0 = *(const float2*)&xb[(size_t)s0 * OBS + l * 2];
        float2 u1 = *(const float2*)&xb[(size_t)s1 * OBS + l * 2];
        float2 u2 = *(const float2*)&xb[(size_t)s2 * OBS + l * 2];
        float2 u3 = *(const float2*)&xb[(size_t)s3 * OBS + l * 2];
        ax = fmaf(w0, u0.x, ax); ay = fmaf(w0, u0.y, ay);
        bx = fmaf(w1, u1.x, bx); by = fmaf(w1, u1.y, by);
        ax = fmaf(w2, u2.x, ax); ay = fmaf(w2, u2.y, ay);
        bx = fmaf(w3, u3.x, bx); by = fmaf(w3, u3.y, by);
    }
    for (; e < degc; ++e) {
        int s = __shfl(s_t, e);
        float w = di * __shfl(dv_t, e);
        float2 u = *(const float2*)&xb[(size_t)s * OBS + l * 2];
        ax = fmaf(w, u.x, ax);
        ay = fmaf(w, u.y, ay);
    }
    ax += bx;
    ay += by;
    z0[(((size_t)b * NN + i) * OBS + l * 2) >> 1] = packbf(ax, ay);
}

// z1 = S . x1  (bf16 in -> bf16 out, F=256; 4 bf16/lane)
__global__ __launch_bounds__(256) void k_agg1(const short* __restrict__ x1,
                                              const int* __restrict__ cnt,
                                              const int* __restrict__ bucket,
                                              unsigned* __restrict__ z1) {
    const int b = blockIdx.y, t = threadIdx.x;
    const int i = blockIdx.x * 4 + (t >> 6);
    const int l = t & 63;
    const int* cb = cnt + b * NN;
    const int deg = cb[i];
    const int degc = deg < BCAP ? deg : BCAP;
    const float di = rsqrtf((float)(deg + 1));
    int s_t = 0;
    float dv_t = 0.f;
    if (l < degc) {
        s_t = bucket[((size_t)b * NN + i) * BCAP + l];
        dv_t = rsqrtf((float)(cb[s_t] + 1));
    }
    const short* xb = x1 + (size_t)b * NN * HID;
    uint2 raw = *(const uint2*)&xb[(size_t)i * HID + l * 4];
    const float di2 = di * di;
    float a0 = di2 * __uint_as_float(raw.x << 16);
    float a1 = di2 * __uint_as_float(raw.x & 0xffff0000u);
    float a2 = di2 * __uint_as_float(raw.y << 16);
    float a3 = di2 * __uint_as_float(raw.y & 0xffff0000u);
    float c0 = 0.f, c1 = 0.f, c2 = 0.f, c3 = 0.f;
    int e = 0;
    for (; e + 4 <= degc; e += 4) {
        int s0 = __shfl(s_t, e),     s1 = __shfl(s_t, e + 1);
        int s2 = __shfl(s_t, e + 2), s3 = __shfl(s_t, e + 3);
        float w0 = di * __shfl(dv_t, e),     w1 = di * __shfl(dv_t, e + 1);
        float w2 = di * __shfl(dv_t, e + 2), w3 = di * __shfl(dv_t, e + 3);
        uint2 u0 = *(const uint2*)&xb[(size_t)s0 * HID + l * 4];
        uint2 u1 = *(const uint2*)&xb[(size_t)s1 * HID + l * 4];
        uint2 u2 = *(const uint2*)&xb[(size_t)s2 * HID + l * 4];
        uint2 u3 = *(const uint2*)&xb[(size_t)s3 * HID + l * 4];
        a0 = fmaf(w0, __uint_as_float(u0.x << 16), a0);
        a1 = fmaf(w0, __uint_as_float(u0.x & 0xffff0000u), a1);
        a2 = fmaf(w0, __uint_as_float(u0.y << 16), a2);
        a3 = fmaf(w0, __uint_as_float(u0.y & 0xffff0000u), a3);
        c0 = fmaf(w1, __uint_as_float(u1.x << 16), c0);
        c1 = fmaf(w1, __uint_as_float(u1.x & 0xffff0000u), c1);
        c2 = fmaf(w1, __uint_as_float(u1.y << 16), c2);
        c3 = fmaf(w1, __uint_as_float(u1.y & 0xffff0000u), c3);
        a0 = fmaf(w2, __uint_as_float(u2.x << 16), a0);
        a1 = fmaf(w2, __uint_as_float(u2.x & 0xffff0000u), a1);
        a2 = fmaf(w2, __uint_as_float(u2.y << 16), a2);
        a3 = fmaf(w2, __uint_as_float(u2.y & 0xffff0000u), a3);
        c0 = fmaf(w3, __uint_as_float(u3.x << 16), c0);
        c1 = fmaf(w3, __uint_as_float(u3.x & 0xffff0000u), c1);
        c2 = fmaf(w3, __uint_as_float(u3.y << 16), c2);
        c3 = fmaf(w3, __uint_as_float(u3.y & 0xffff0000u), c3);
    }
    for (; e < degc; ++e) {
        int s = __shfl(s_t, e);
        float w = di * __shfl(dv_t, e);
        uint2 u = *(const uint2*)&xb[(size_t)s * HID + l * 4];
        a0 = fmaf(w, __uint_as_float(u.x << 16), a0);
        a1 = fmaf(w, __uint_as_float(u.x & 0xffff0000u), a1);
        a2 = fmaf(w, __uint_as_float(u.y << 16), a2);
        a3 = fmaf(w, __uint_as_float(u.y & 0xffff0000u), a3);
    }
    a0 += c0; a1 += c1; a2 += c2; a3 += c3;
    uint2 o;
    o.x = packbf(a0, a1);
    o.y = packbf(a2, a3);
    *(uint2*)&z1[(((size_t)b * NN + i) * HID + l * 4) >> 1] = o;
}

// ---------------- gemm1: 128x128 tile, BK=32, 256 thr (proven R9 shape) ----------------
template <int K, int N, bool OUT_BF16, int BK>
__global__ __launch_bounds__(256, 3) void gemm_mfma(const short* __restrict__ A,
                                                    const short* __restrict__ Bt,
                                                    const float* __restrict__ bias,
                                                    void* __restrict__ Cv) {
    __shared__ short lds[2][2][128 * BK];
    constexpr int NC = N / 128;
    constexpr int CH = (128 * BK * 2) / 4096;
    const int h = blockIdx.x;
    const int rtile = (h & 7) + 8 * (h / (8 * NC));
    const int ctile = (h >> 3) % NC;
    const int tid = threadIdx.x;
    const int lane = tid & 63;
    const int wid = tid >> 6;
    const int wr = wid >> 1, wc = wid & 1;
    const int lrow = lane & 15, lk = (lane >> 4) * 8;
    const int row0 = rtile * 128, col0 = ctile * 128;
    const short* gA = A + (size_t)row0 * K;
    const short* gB = Bt + (size_t)col0 * K;

    auto stage = [&](int buf, int kt) {
#pragma unroll
        for (int c = 0; c < CH; ++c) {
            int off = c * 4096 + tid * 16;
            int row = off / (2 * BK), kb = (off % (2 * BK)) >> 1;
            gload_lds16(gA + (size_t)row * K + kt + kb, (char*)&lds[buf][0][0] + off);
            gload_lds16(gB + (size_t)row * K + kt + kb, (char*)&lds[buf][1][0] + off);
        }
    };

    ffrag acc[4][4] = {};
    stage(0, 0);
    __syncthreads();
    const int NT = K / BK;
    int cur = 0;
    for (int kt = 0; kt < NT; ++kt) {
        if (kt + 1 < NT) stage(cur ^ 1, (kt + 1) * BK);
        const short* As = &lds[cur][0][0];
        const short* Bs = &lds[cur][1][0];
#pragma unroll
        for (int kk = 0; kk < BK / 32; ++kk) {
            bfrag a[4], b[4];
#pragma unroll
            for (int m = 0; m < 4; ++m)
                a[m] = *(const bfrag*)&As[(wr * 64 + m * 16 + lrow) * BK + kk * 32 + lk];
#pragma unroll
            for (int n = 0; n < 4; ++n)
                b[n] = *(const bfrag*)&Bs[(wc * 64 + n * 16 + lrow) * BK + kk * 32 + lk];
#pragma unroll
            for (int m = 0; m < 4; ++m)
#pragma unroll
                for (int n = 0; n < 4; ++n)
                    acc[m][n] = __builtin_amdgcn_mfma_f32_16x16x32_bf16(a[m], b[n], acc[m][n], 0, 0, 0);
        }
        __syncthreads();
        cur ^= 1;
    }

    const int orow = row0 + wr * 64 + (lane >> 4) * 4;
    const int ocol = col0 + wc * 64 + lrow;
#pragma unroll
    for (int n = 0; n < 4; ++n) {
        float bv = bias[ocol + n * 16];
#pragma unroll
        for (int m = 0; m < 4; ++m) {
#pragma unroll
            for (int r = 0; r < 4; ++r) {
                float v = fmaxf(acc[m][n][r] + bv, 0.f);
                size_t idx = (size_t)(orow + m * 16 + r) * N + (ocol + n * 16);
                if constexpr (OUT_BF16)
                    ((short*)Cv)[idx] = f2bf(v);
                else
                    ((float*)Cv)[idx] = v;
            }
        }
    }
}

// ---------------- gemm2: 128x256 tile, BK=32, 512 thr (8 waves 2x4) ----------------
// 512 blocks, 48KB LDS, 2 blocks/CU -> all blocks resident in one round.
template <int K>
__global__ __launch_bounds__(512, 4) void gemm_wide(const short* __restrict__ A,
                                                    const short* __restrict__ Bt,
                                                    const float* __restrict__ bias,
                                                    float* __restrict__ C) {
    constexpr int N = OUTF, BK = 32, BM = 128, BN = 256;
    __shared__ short lds[2][(BM + BN) * BK];  // A at 0 (8KB), B at BM*BK (16KB)
    const int h = blockIdx.x;                  // 512 blocks: 128 rtiles x 4 ctiles
    const int rtile = (h & 7) + 8 * (h >> 5); // XCD-grouped, bijective (512 % 32 == 0)
    const int ctile = (h >> 3) & 3;
    const int tid = threadIdx.x;
    const int lane = tid & 63, wid = tid >> 6;
    const int wr = wid >> 2, wc = wid & 3;    // 2x4 wave grid, 64x64 per wave
    const int lrow = lane & 15, lk = (lane >> 4) * 8;
    const short* gA = A + (size_t)(rtile * BM) * K;
    const short* gB = Bt + (size_t)(ctile * BN) * K;

    auto stage = [&](int buf, int kt) {
        {
            int off = tid * 16;                       // A: 8KB, 1 chunk
            int row = off >> 6, kb = (off & 63) >> 1; // 2*BK=64 B per row
            gload_lds16(gA + (size_t)row * K + kt + kb, (char*)&lds[buf][0] + off);
        }
#pragma unroll
        for (int c = 0; c < 2; ++c) {                 // B: 16KB, 2 chunks
            int off = c * 8192 + tid * 16;
            int row = off >> 6, kb = (off & 63) >> 1;
            gload_lds16(gB + (size_t)row * K + kt + kb, (char*)&lds[buf][BM * BK] + off);
        }
    };

    ffrag acc[4][4] = {};
    stage(0, 0);
    __syncthreads();
    const int NT = K / BK;  // 8
    int cur = 0;
    for (int kt = 0; kt < NT; ++kt) {
        if (kt + 1 < NT) stage(cur ^ 1, (kt + 1) * BK);
        const short* As = &lds[cur][0];
        const short* Bs = &lds[cur][BM * BK];
        bfrag a[4], b[4];
#pragma unroll
        for (int m = 0; m < 4; ++m)
            a[m] = *(const bfrag*)&As[(wr * 64 + m * 16 + lrow) * BK + lk];
#pragma unroll
        for (int n = 0; n < 4; ++n)
            b[n] = *(const bfrag*)&Bs[(wc * 64 + n * 16 + lrow) * BK + lk];
#pragma unroll
        for (int m = 0; m < 4; ++m)
#pragma unroll
            for (int n = 0; n < 4; ++n)
                acc[m][n] = __builtin_amdgcn_mfma_f32_16x16x32_bf16(a[m], b[n], acc[m][n], 0, 0, 0);
        __syncthreads();
        cur ^= 1;
    }

    const int orow = rtile * BM + wr * 64 + (lane >> 4) * 4;
    const int ocol = ctile * BN + wc * 64 + lrow;
#pragma unroll
    for (int n = 0; n < 4; ++n) {
        float bv = bias[ocol + n * 16];
#pragma unroll
        for (int m = 0; m < 4; ++m)
#pragma unroll
            for (int r = 0; r < 4; ++r) {
                float v = fmaxf(acc[m][n][r] + bv, 0.f);
                C[(size_t)(orow + m * 16 + r) * N + ocol + n * 16] = v;
            }
    }
}

extern "C" void kernel_launch(void* const* d_in, const int* in_sizes, int n_in,
                              void* d_out, int out_size, void* d_ws, size_t ws_size,
                              hipStream_t stream) {
    const float* nodes = (const float*)d_in[0];
    const int*   edges = (const int*)d_in[1];
    const float* W0    = (const float*)d_in[2];
    const float* b0    = (const float*)d_in[3];
    const float* W1    = (const float*)d_in[4];
    const float* b1    = (const float*)d_in[5];
    float* out = (float*)d_out;

    char* ws = (char*)d_ws;
    size_t off = 0;
    auto alloc = [&](size_t bytes) -> char* {
        char* p = ws + off;
        off = (off + bytes + 255) & ~(size_t)255;
        return p;
    };
    int*   cnt    = (int*)alloc((size_t)NB * NN * 4);
    int*   bucket = (int*)alloc((size_t)NB * NN * BCAP * 4);   // 4 MB
    short* W0t    = (short*)alloc((size_t)HID * OBS * 2);
    short* W1t    = (short*)alloc((size_t)OUTF * HID * 2);
    short* z0     = (short*)alloc((size_t)NB * NN * OBS * 2);  // 4 MB
    short* x1     = (short*)alloc((size_t)NB * NN * HID * 2);  // 8 MB
    short* z1     = (short*)alloc((size_t)NB * NN * HID * 2);  // 8 MB

    k_prep<<<(HID * OUTF + 255) / 256, 256, 0, stream>>>(W0, W1, W0t, W1t, cnt);
    k_bucket<<<(NB * NE + 255) / 256, 256, 0, stream>>>(edges, cnt, bucket);
    k_agg0<<<dim3(NN / 4, NB), 256, 0, stream>>>(nodes, cnt, bucket, (unsigned*)z0);
    gemm_mfma<OBS, HID, true, 32><<<(NB * NN / 128) * (HID / 128), 256, 0, stream>>>(z0, W0t, b0, x1);
    k_agg1<<<dim3(NN / 4, NB), 256, 0, stream>>>(x1, cnt, bucket, (unsigned*)z1);
    gemm_wide<HID><<<(NB * NN / 128) * (OUTF / 256), 512, 0, stream>>>(z1, W1t, b1, out);
}